// Round 18
// baseline (1797.619 us; speedup 1.0000x reference)
//
#include <hip/hip_runtime.h>
#include <math.h>

#define NROWS 8192
#define DIM   64
#define KSEL  32
#define NQ    (NROWS - KSEL)   /* 8160 query rows */
#define P1LEN 512              /* exact prefix length */
#define CAP   1024             /* per-query candidate list capacity */
#define TL    64               /* GEMM tile edge (queries and candidates) */

// ---------------------------------------------------------------------------
// Kernel A: row norms replicating XLA:CPU (LLVM-vectorized fused reduce):
//   VF=8 lanes, init 0, per-lane FMA chain, horizontal shuffle-tree
//   ((r0+r4)+(r2+r6)) + ((r1+r5)+(r3+r7)).   [validated bit-exact R8-R17]
// ---------------------------------------------------------------------------
__global__ void norms_kernel(const float* __restrict__ x, float* __restrict__ sq) {
    int j = blockIdx.x * blockDim.x + threadIdx.x;
    if (j >= NROWS) return;
    const float* xr = x + (size_t)j * DIM;
    float r[8];
#pragma unroll
    for (int u = 0; u < 8; ++u) r[u] = 0.0f;
#pragma unroll
    for (int i = 0; i < DIM; i += 8) {
#pragma unroll
        for (int u = 0; u < 8; ++u)
            r[u] = __fmaf_rn(xr[i + u], xr[i + u], r[u]);
    }
    const float s04 = __fadd_rn(r[0], r[4]);
    const float s26 = __fadd_rn(r[2], r[6]);
    const float s15 = __fadd_rn(r[1], r[5]);
    const float s37 = __fadd_rn(r[3], r[7]);
    sq[j] = __fadd_rn(__fadd_rn(s04, s26), __fadd_rn(s15, s37));
}

// ---------------------------------------------------------------------------
// Stage a 64-row x 64-dim tile TRANSPOSED into T[k*64 + row].
// row = lane (tid&63): within a wave all 64 rows distinct -> bank =
// row%32 -> 2-way aliasing only (free).  4x float4 per thread.
// ---------------------------------------------------------------------------
__device__ __forceinline__ void stage64(const float* __restrict__ x,
                                        int base_row, float* T, int tid) {
    const int row   = tid & 63;
    const int dbase = (tid >> 6) * 16;     // wave id * 16 dims
    const int r     = min(base_row + row, NROWS - 1);
    const float4* src =
        reinterpret_cast<const float4*>(x + (size_t)r * DIM + dbase);
#pragma unroll
    for (int i = 0; i < 4; ++i) {
        float4 v = src[i];
        const int d = dbase + i * 4;
        T[(d + 0) * TL + row] = v.x;
        T[(d + 1) * TL + row] = v.y;
        T[(d + 2) * TL + row] = v.z;
        T[(d + 3) * TL + row] = v.w;
    }
}

// ---------------------------------------------------------------------------
// 64x64 GEMM body, 4x4 micro-tile, 16x16 thread grid.  Explicit 1-step
// register prefetch: k+1's operands are loaded before k's FMAs so LDS
// latency overlaps FMA issue.  Qs read = 4-address broadcast (free);
// Cs read = stride-16B 2-way (free).  Each acc[a][b] = single fp32 FMA
// chain over k=0..63 ascending == validated bit-exact Eigen/XLA chain.
// ---------------------------------------------------------------------------
__device__ __forceinline__ void gemm64(const float* Qs, const float* Cs,
                                       float acc[4][4], int tx, int ty) {
    float4 qn = *reinterpret_cast<const float4*>(&Qs[0 * TL + ty * 4]);
    float4 cn = *reinterpret_cast<const float4*>(&Cs[0 * TL + tx * 4]);
#pragma unroll
    for (int k = 0; k < DIM; ++k) {
        const float4 q = qn, c = cn;
        if (k + 1 < DIM) {
            qn = *reinterpret_cast<const float4*>(&Qs[(k + 1) * TL + ty * 4]);
            cn = *reinterpret_cast<const float4*>(&Cs[(k + 1) * TL + tx * 4]);
        }
        acc[0][0] = __fmaf_rn(q.x, c.x, acc[0][0]);
        acc[0][1] = __fmaf_rn(q.x, c.y, acc[0][1]);
        acc[0][2] = __fmaf_rn(q.x, c.z, acc[0][2]);
        acc[0][3] = __fmaf_rn(q.x, c.w, acc[0][3]);
        acc[1][0] = __fmaf_rn(q.y, c.x, acc[1][0]);
        acc[1][1] = __fmaf_rn(q.y, c.y, acc[1][1]);
        acc[1][2] = __fmaf_rn(q.y, c.z, acc[1][2]);
        acc[1][3] = __fmaf_rn(q.y, c.w, acc[1][3]);
        acc[2][0] = __fmaf_rn(q.z, c.x, acc[2][0]);
        acc[2][1] = __fmaf_rn(q.z, c.y, acc[2][1]);
        acc[2][2] = __fmaf_rn(q.z, c.z, acc[2][2]);
        acc[2][3] = __fmaf_rn(q.z, c.w, acc[2][3]);
        acc[3][0] = __fmaf_rn(q.w, c.x, acc[3][0]);
        acc[3][1] = __fmaf_rn(q.w, c.y, acc[3][1]);
        acc[3][2] = __fmaf_rn(q.w, c.z, acc[3][2]);
        acc[3][3] = __fmaf_rn(q.w, c.w, acc[3][3]);
    }
}

// ---------------------------------------------------------------------------
// Prefix GEMM: keys for candidates [0, 512) written DIRECT-INDEXED to
// lists[qi][j] (no atomics).  Invalid (j >= r) -> ~0ull.
// dist = fl(fl(sqr+sqj) - fl(2*dot)) clamped at 0 (bit-exact, validated).
// ---------------------------------------------------------------------------
__global__ __launch_bounds__(256)
void prefix_kernel(const float* __restrict__ x, const float* __restrict__ sq,
                   unsigned long long* __restrict__ lists) {
    const int qb = blockIdx.x;             // 0..127
    const int jb = blockIdx.y * TL;        // 0..448
    const int Rq = KSEL + qb * TL;

    __shared__ float Qs[DIM * TL];         // 16 KB
    __shared__ float Cs[DIM * TL];         // 16 KB
    __shared__ float sqq[TL], sqc[TL];

    const int tid = threadIdx.x;
    stage64(x, Rq, Qs, tid);
    stage64(x, jb, Cs, tid);
    if (tid < TL) {
        const int rq = Rq + tid;
        sqq[tid] = (rq < NROWS) ? sq[rq] : 0.0f;
    } else if (tid < 2 * TL) {
        sqc[tid - TL] = sq[jb + (tid - TL)];
    }
    __syncthreads();

    const int tx = tid & 15, ty = tid >> 4;
    float acc[4][4] = {{0.f}};
    gemm64(Qs, Cs, acc, tx, ty);

#pragma unroll
    for (int a = 0; a < 4; ++a) {
        const int ql = ty * 4 + a;
        const int rq = Rq + ql;
        if (rq >= NROWS) continue;
        const int qi = rq - KSEL;
        const float sqr = sqq[ql];
#pragma unroll
        for (int b = 0; b < 4; ++b) {
            const int cl = tx * 4 + b;
            const int j = jb + cl;
            const float dd = fmaxf(
                __fsub_rn(__fadd_rn(sqr, sqc[cl]),
                          __fmul_rn(2.0f, acc[a][b])), 0.0f);
            unsigned long long key =
                ((unsigned long long)__float_as_uint(dd) << 32) | (unsigned)j;
            if (j >= rq) key = ~0ull;
            lists[(size_t)qi * CAP + j] = key;
        }
    }
}

// ---------------------------------------------------------------------------
// Tau-select: ONE WAVE per query.  Coalesced read of the 512 prefix keys,
// 32 shuffle-only extract-min iterations (u64-min = ascending (dist, idx),
// low-index ties).  Writes exact top-32 to lists[qi][0..31], tau0, cnt=32.
// ---------------------------------------------------------------------------
__global__ __launch_bounds__(64)
void tausel_kernel(unsigned long long* __restrict__ lists,
                   unsigned long long* __restrict__ tau0,
                   unsigned int* __restrict__ cnt) {
    const int qi   = blockIdx.x;
    const int lane = threadIdx.x;
    unsigned long long* src = lists + (size_t)qi * CAP;

    unsigned long long k[8];
#pragma unroll
    for (int s = 0; s < 8; ++s) k[s] = src[lane + (s << 6)];

    unsigned long long pmin = ~0ull;
#pragma unroll
    for (int s = 0; s < 8; ++s) pmin = k[s] < pmin ? k[s] : pmin;

    unsigned long long g = ~0ull;
    for (int it = 0; it < KSEL; ++it) {
        unsigned long long v = pmin;
#pragma unroll
        for (int off = 32; off > 0; off >>= 1) {
            const unsigned long long o = __shfl_down(v, off, 64);
            v = o < v ? o : v;
        }
        g = __shfl(v, 0, 64);
        if (lane == 0) src[it] = g;
        if (pmin == g) {
#pragma unroll
            for (int s = 0; s < 8; ++s) if (k[s] == g) k[s] = ~0ull;
            pmin = ~0ull;
#pragma unroll
            for (int s = 0; s < 8; ++s) pmin = k[s] < pmin ? k[s] : pmin;
        }
    }
    if (lane == 0) { tau0[qi] = g; cnt[qi] = KSEL; }
}

// ---------------------------------------------------------------------------
// Pass 2: tail GEMM filter over candidates [512, r).  64x64 tile,
// conflict-free staging + register-prefetch k-loop.  Accept bits(dist) <=
// tau_hi (safe superset: 32nd-of-prefix >= 32nd-overall), atomic append.
// ---------------------------------------------------------------------------
__global__ __launch_bounds__(256)
void pass2_kernel(const float* __restrict__ x, const float* __restrict__ sq,
                  const unsigned long long* __restrict__ tau0,
                  unsigned int* __restrict__ cnt,
                  unsigned long long* __restrict__ lists) {
    const int qb   = blockIdx.x;                        // 0..127
    const int jb   = P1LEN + blockIdx.y * TL;           // 512..8128
    const int Rq   = KSEL + qb * TL;
    const int r_hi = min(Rq + TL, NROWS);
    if (jb >= r_hi) return;                             // uniform exit

    __shared__ float Qs[DIM * TL];
    __shared__ float Cs[DIM * TL];
    __shared__ float sqq[TL], sqc[TL];
    __shared__ unsigned tauh[TL];

    const int tid = threadIdx.x;
    stage64(x, Rq, Qs, tid);
    stage64(x, jb, Cs, tid);
    if (tid < TL) {
        const int rq = Rq + tid;
        const bool v = (rq < NROWS);
        sqq[tid]  = v ? sq[rq] : 0.0f;
        tauh[tid] = v ? (unsigned)(tau0[rq - KSEL] >> 32) : 0u;
    } else if (tid < 2 * TL) {
        sqc[tid - TL] = sq[jb + (tid - TL)];
    }
    __syncthreads();

    const int tx = tid & 15, ty = tid >> 4;
    float acc[4][4] = {{0.f}};
    gemm64(Qs, Cs, acc, tx, ty);

#pragma unroll
    for (int a = 0; a < 4; ++a) {
        const int ql = ty * 4 + a;
        const int rq = Rq + ql;
        if (rq >= NROWS) continue;
        const int qi = rq - KSEL;
        const float sqr = sqq[ql];
        const unsigned th = tauh[ql];
#pragma unroll
        for (int b = 0; b < 4; ++b) {
            const int cl = tx * 4 + b;
            const int j = jb + cl;
            const float dd = fmaxf(
                __fsub_rn(__fadd_rn(sqr, sqc[cl]),
                          __fmul_rn(2.0f, acc[a][b])), 0.0f);
            const unsigned bits = __float_as_uint(dd);
            if (j < rq && bits <= th) {
                const unsigned s = atomicAdd(&cnt[qi], 1u);
                if (s < CAP)
                    lists[(size_t)qi * CAP + s] =
                        ((unsigned long long)bits << 32) | (unsigned)j;
            }
        }
    }
}

// ---------------------------------------------------------------------------
// Merge: ONE WAVE per query.  16 keys/lane in registers, 32 shuffle-only
// extract-min iterations (validated).  List is a superset of true top-32.
// ---------------------------------------------------------------------------
__global__ __launch_bounds__(64)
void merge_kernel(const unsigned long long* __restrict__ lists,
                  const unsigned int* __restrict__ cnt,
                  float* __restrict__ out_d, float* __restrict__ out_i) {
    const int qi   = blockIdx.x;
    const int lane = threadIdx.x;
    const int ne   = min((int)cnt[qi], CAP);
    const unsigned long long* src = lists + (size_t)qi * CAP;

    unsigned long long k[16];
#pragma unroll
    for (int s = 0; s < 16; ++s) {
        const int idx = lane + (s << 6);
        k[s] = (idx < ne) ? src[idx] : ~0ull;
    }
    unsigned long long pmin = ~0ull;
#pragma unroll
    for (int s = 0; s < 16; ++s) pmin = k[s] < pmin ? k[s] : pmin;

    for (int it = 0; it < KSEL; ++it) {
        unsigned long long v = pmin;
#pragma unroll
        for (int off = 32; off > 0; off >>= 1) {
            const unsigned long long o = __shfl_down(v, off, 64);
            v = o < v ? o : v;
        }
        const unsigned long long g = __shfl(v, 0, 64);
        if (lane == 0) {
            out_d[(size_t)qi * KSEL + it] = __uint_as_float((unsigned)(g >> 32));
            out_i[(size_t)qi * KSEL + it] = (float)(unsigned)(g & 0xFFFFFFFFu);
        }
        if (pmin == g) {
#pragma unroll
            for (int s = 0; s < 16; ++s) if (k[s] == g) k[s] = ~0ull;
            pmin = ~0ull;
#pragma unroll
            for (int s = 0; s < 16; ++s) pmin = k[s] < pmin ? k[s] : pmin;
        }
    }
}

extern "C" void kernel_launch(void* const* d_in, const int* in_sizes, int n_in,
                              void* d_out, int out_size, void* d_ws, size_t ws_size,
                              hipStream_t stream) {
    const float* x = (const float*)d_in[0];    // anchor_x [8192, 64] fp32
    float* sq = (float*)d_ws;                                        // 32 KB
    unsigned long long* tau0 =
        (unsigned long long*)((char*)d_ws + 32768);                  // 64 KB
    unsigned int* cnt = (unsigned int*)((char*)d_ws + 98304);        // 32 KB
    unsigned long long* lists =
        (unsigned long long*)((char*)d_ws + 131072);                 // 66.8 MB
    float* out_d = (float*)d_out;              // [8160, 32] distances
    float* out_i = out_d + (size_t)NQ * KSEL;  // [8160, 32] indices (as fp32)

    norms_kernel<<<NROWS / 256, 256, 0, stream>>>(x, sq);
    dim3 gp(128, P1LEN / TL);                  // prefix: 128 qtiles x 8 ctiles
    prefix_kernel<<<gp, 256, 0, stream>>>(x, sq, lists);
    tausel_kernel<<<NQ, 64, 0, stream>>>(lists, tau0, cnt);
    dim3 g2(128, (NROWS - P1LEN) / TL);        // tail: 128 x 120
    pass2_kernel<<<g2, 256, 0, stream>>>(x, sq, tau0, cnt, lists);
    merge_kernel<<<NQ, 64, 0, stream>>>(lists, cnt, out_d, out_i);
}

// Round 19
// 404.168 us; speedup vs baseline: 4.4477x; 4.4477x over previous
//
#include <hip/hip_runtime.h>
#include <math.h>

#define NROWS 8192
#define DIM   64
#define KSEL  32
#define NQ    (NROWS - KSEL)   /* 8160 query rows */
#define P1LEN 512              /* exact prefix length */
#define CAP   1024             /* per-query candidate list capacity */
#define TLQ   128              /* queries per GEMM tile */
#define TLC   128              /* candidates per GEMM tile */
#define KS    32               /* k-split depth (two phases of 32) */

// ---------------------------------------------------------------------------
// Kernel A: row norms replicating XLA:CPU (LLVM-vectorized fused reduce):
//   VF=8 lanes, init 0, per-lane FMA chain, horizontal shuffle-tree
//   ((r0+r4)+(r2+r6)) + ((r1+r5)+(r3+r7)).   [validated bit-exact R8-R18]
// ---------------------------------------------------------------------------
__global__ void norms_kernel(const float* __restrict__ x, float* __restrict__ sq) {
    int j = blockIdx.x * blockDim.x + threadIdx.x;
    if (j >= NROWS) return;
    const float* xr = x + (size_t)j * DIM;
    float r[8];
#pragma unroll
    for (int u = 0; u < 8; ++u) r[u] = 0.0f;
#pragma unroll
    for (int i = 0; i < DIM; i += 8) {
#pragma unroll
        for (int u = 0; u < 8; ++u)
            r[u] = __fmaf_rn(xr[i + u], xr[i + u], r[u]);
    }
    const float s04 = __fadd_rn(r[0], r[4]);
    const float s26 = __fadd_rn(r[2], r[6]);
    const float s15 = __fadd_rn(r[1], r[5]);
    const float s37 = __fadd_rn(r[3], r[7]);
    sq[j] = __fadd_rn(__fadd_rn(s04, s26), __fadd_rn(s15, s37));
}

// ---------------------------------------------------------------------------
// Stage HALF-K of a 128-row tile transposed: T[dk*128 + row], dims
// [kb*32, kb*32+32).  row = tid>>1 -> 2-way bank aliasing only (free).
// ---------------------------------------------------------------------------
__device__ __forceinline__ void stage_half(const float* __restrict__ x,
                                           int base_row, int kb,
                                           float* T, int tid) {
    const int row   = tid >> 1;                 // 0..127
    const int dbase = kb * KS + (tid & 1) * 16; // 16 dims per thread
    const int r     = min(base_row + row, NROWS - 1);
    const float4* src =
        reinterpret_cast<const float4*>(x + (size_t)r * DIM + dbase);
#pragma unroll
    for (int i = 0; i < 4; ++i) {
        float4 v = src[i];
        const int dk = (tid & 1) * 16 + i * 4;  // local k 0..31
        T[(dk + 0) * 128 + row] = v.x;
        T[(dk + 1) * 128 + row] = v.y;
        T[(dk + 2) * 128 + row] = v.z;
        T[(dk + 3) * 128 + row] = v.w;
    }
}

// ---------------------------------------------------------------------------
// Split 8x8 micro-tile over one 32-deep K phase.  Thread (tx,ty) owns
// queries {ty*4..+4} u {64+ty*4..+4}, candidates {tx*4..+4} u {64+tx*4..+4}.
// Qs reads broadcast, Cs stride-4 2-way (free).  acc chains continue in
// ascending k across phases == validated bit-exact Eigen/XLA dot chain.
// NO manual prefetch (R18: hoisting blows VGPR to 256).  unroll 2 only.
// ---------------------------------------------------------------------------
#define GEMM_PHASE(Qs, Cs, acc, tx, ty)                                        \
    _Pragma("unroll 2")                                                        \
    for (int dk = 0; dk < KS; ++dk) {                                          \
        const float4 q0 = *reinterpret_cast<const float4*>(&Qs[dk * 128 + (ty) * 4]);      \
        const float4 q1 = *reinterpret_cast<const float4*>(&Qs[dk * 128 + 64 + (ty) * 4]); \
        const float4 c0 = *reinterpret_cast<const float4*>(&Cs[dk * 128 + (tx) * 4]);      \
        const float4 c1 = *reinterpret_cast<const float4*>(&Cs[dk * 128 + 64 + (tx) * 4]); \
        const float qv[8] = {q0.x, q0.y, q0.z, q0.w, q1.x, q1.y, q1.z, q1.w};  \
        const float cv[8] = {c0.x, c0.y, c0.z, c0.w, c1.x, c1.y, c1.z, c1.w};  \
        _Pragma("unroll")                                                      \
        for (int a = 0; a < 8; ++a)                                            \
            _Pragma("unroll")                                                  \
            for (int b = 0; b < 8; ++b)                                        \
                acc[a][b] = __fmaf_rn(qv[a], cv[b], acc[a][b]);                \
    }

__device__ __forceinline__ int qlocal(int ty, int a) {
    return (a < 4) ? (ty * 4 + a) : (64 + ty * 4 + (a - 4));
}
__device__ __forceinline__ int clocal(int tx, int b) {
    return (b < 4) ? (tx * 4 + b) : (64 + tx * 4 + (b - 4));
}

// ---------------------------------------------------------------------------
// Prefix GEMM (half-K staged): keys for candidates [0, 512) written
// DIRECT-INDEXED to lists[qi][j].  Invalid (j >= r) -> ~0ull.
// dist = fl(fl(sqr+sqj) - fl(2*dot)) clamped at 0 (bit-exact, validated).
// ---------------------------------------------------------------------------
__global__ __launch_bounds__(256)
void prefix_kernel(const float* __restrict__ x, const float* __restrict__ sq,
                   unsigned long long* __restrict__ lists) {
    const int qb = blockIdx.x;             // 0..63
    const int jb = blockIdx.y * TLC;       // 0,128,256,384
    const int Rq = KSEL + qb * TLQ;

    __shared__ float Qs[KS * 128];         // 16 KB
    __shared__ float Cs[KS * 128];         // 16 KB
    __shared__ float sqq[TLQ], sqc[TLC];

    const int tid = threadIdx.x;
    stage_half(x, Rq, 0, Qs, tid);
    stage_half(x, jb, 0, Cs, tid);
    if (tid < TLQ) {
        const int rq = Rq + tid;
        sqq[tid] = (rq < NROWS) ? sq[rq] : 0.0f;
    } else {
        sqc[tid - 128] = sq[jb + (tid - 128)];
    }
    __syncthreads();

    const int tx = tid & 15, ty = tid >> 4;
    float acc[8][8] = {{0.f}};
    GEMM_PHASE(Qs, Cs, acc, tx, ty)
    __syncthreads();
    stage_half(x, Rq, 1, Qs, tid);
    stage_half(x, jb, 1, Cs, tid);
    __syncthreads();
    GEMM_PHASE(Qs, Cs, acc, tx, ty)

#pragma unroll
    for (int a = 0; a < 8; ++a) {
        const int ql = qlocal(ty, a);
        const int rq = Rq + ql;
        if (rq >= NROWS) continue;
        const int qi = rq - KSEL;
        const float sqr = sqq[ql];
#pragma unroll
        for (int b = 0; b < 8; ++b) {
            const int cl = clocal(tx, b);
            const int j = jb + cl;
            const float dd = fmaxf(
                __fsub_rn(__fadd_rn(sqr, sqc[cl]),
                          __fmul_rn(2.0f, acc[a][b])), 0.0f);
            unsigned long long key =
                ((unsigned long long)__float_as_uint(dd) << 32) | (unsigned)j;
            if (j >= rq) key = ~0ull;
            lists[(size_t)qi * CAP + j] = key;
        }
    }
}

// ---------------------------------------------------------------------------
// Tau-select: ONE WAVE per query.  Coalesced read of the 512 prefix keys,
// 32 shuffle-only extract-min iterations (u64-min = ascending (dist, idx),
// low-index ties).  Writes exact top-32 to lists[qi][0..31], tau0, cnt=32.
// ---------------------------------------------------------------------------
__global__ __launch_bounds__(64)
void tausel_kernel(unsigned long long* __restrict__ lists,
                   unsigned long long* __restrict__ tau0,
                   unsigned int* __restrict__ cnt) {
    const int qi   = blockIdx.x;
    const int lane = threadIdx.x;
    unsigned long long* src = lists + (size_t)qi * CAP;

    unsigned long long k[8];
#pragma unroll
    for (int s = 0; s < 8; ++s) k[s] = src[lane + (s << 6)];

    unsigned long long pmin = ~0ull;
#pragma unroll
    for (int s = 0; s < 8; ++s) pmin = k[s] < pmin ? k[s] : pmin;

    unsigned long long g = ~0ull;
    for (int it = 0; it < KSEL; ++it) {
        unsigned long long v = pmin;
#pragma unroll
        for (int off = 32; off > 0; off >>= 1) {
            const unsigned long long o = __shfl_down(v, off, 64);
            v = o < v ? o : v;
        }
        g = __shfl(v, 0, 64);
        if (lane == 0) src[it] = g;
        if (pmin == g) {
#pragma unroll
            for (int s = 0; s < 8; ++s) if (k[s] == g) k[s] = ~0ull;
            pmin = ~0ull;
#pragma unroll
            for (int s = 0; s < 8; ++s) pmin = k[s] < pmin ? k[s] : pmin;
        }
    }
    if (lane == 0) { tau0[qi] = g; cnt[qi] = KSEL; }
}

// ---------------------------------------------------------------------------
// Pass 2: tail GEMM filter over candidates [512, r), half-K staged
// 128x128 tile (33.5 KB LDS -> 4 blocks/CU -> 16 waves/CU).
// Accept bits(dist) <= tau_hi (safe superset), append via atomicAdd.
// ---------------------------------------------------------------------------
__global__ __launch_bounds__(256)
void pass2_kernel(const float* __restrict__ x, const float* __restrict__ sq,
                  const unsigned long long* __restrict__ tau0,
                  unsigned int* __restrict__ cnt,
                  unsigned long long* __restrict__ lists) {
    const int qb   = blockIdx.x;                        // 0..63
    const int jb   = P1LEN + blockIdx.y * TLC;          // 512..8064
    const int Rq   = KSEL + qb * TLQ;
    const int r_hi = min(Rq + TLQ, NROWS);
    if (jb >= r_hi) return;                             // uniform exit

    __shared__ float Qs[KS * 128];
    __shared__ float Cs[KS * 128];
    __shared__ float sqq[TLQ], sqc[TLC];
    __shared__ unsigned tauh[TLQ];

    const int tid = threadIdx.x;
    stage_half(x, Rq, 0, Qs, tid);
    stage_half(x, jb, 0, Cs, tid);
    if (tid < TLQ) {
        const int rq = Rq + tid;
        const bool v = (rq < NROWS);
        sqq[tid]  = v ? sq[rq] : 0.0f;
        tauh[tid] = v ? (unsigned)(tau0[rq - KSEL] >> 32) : 0u;
    } else {
        sqc[tid - 128] = sq[jb + (tid - 128)];
    }
    __syncthreads();

    const int tx = tid & 15, ty = tid >> 4;
    float acc[8][8] = {{0.f}};
    GEMM_PHASE(Qs, Cs, acc, tx, ty)
    __syncthreads();
    stage_half(x, Rq, 1, Qs, tid);
    stage_half(x, jb, 1, Cs, tid);
    __syncthreads();
    GEMM_PHASE(Qs, Cs, acc, tx, ty)

#pragma unroll
    for (int a = 0; a < 8; ++a) {
        const int ql = qlocal(ty, a);
        const int rq = Rq + ql;
        if (rq >= NROWS) continue;
        const int qi = rq - KSEL;
        const float sqr = sqq[ql];
        const unsigned th = tauh[ql];
#pragma unroll
        for (int b = 0; b < 8; ++b) {
            const int cl = clocal(tx, b);
            const int j = jb + cl;
            const float dd = fmaxf(
                __fsub_rn(__fadd_rn(sqr, sqc[cl]),
                          __fmul_rn(2.0f, acc[a][b])), 0.0f);
            const unsigned bits = __float_as_uint(dd);
            if (j < rq && bits <= th) {
                const unsigned s = atomicAdd(&cnt[qi], 1u);
                if (s < CAP)
                    lists[(size_t)qi * CAP + s] =
                        ((unsigned long long)bits << 32) | (unsigned)j;
            }
        }
    }
}

// ---------------------------------------------------------------------------
// Merge: ONE WAVE per query.  16 keys/lane in registers, 32 shuffle-only
// extract-min iterations (validated).  List is a superset of true top-32.
// ---------------------------------------------------------------------------
__global__ __launch_bounds__(64)
void merge_kernel(const unsigned long long* __restrict__ lists,
                  const unsigned int* __restrict__ cnt,
                  float* __restrict__ out_d, float* __restrict__ out_i) {
    const int qi   = blockIdx.x;
    const int lane = threadIdx.x;
    const int ne   = min((int)cnt[qi], CAP);
    const unsigned long long* src = lists + (size_t)qi * CAP;

    unsigned long long k[16];
#pragma unroll
    for (int s = 0; s < 16; ++s) {
        const int idx = lane + (s << 6);
        k[s] = (idx < ne) ? src[idx] : ~0ull;
    }
    unsigned long long pmin = ~0ull;
#pragma unroll
    for (int s = 0; s < 16; ++s) pmin = k[s] < pmin ? k[s] : pmin;

    for (int it = 0; it < KSEL; ++it) {
        unsigned long long v = pmin;
#pragma unroll
        for (int off = 32; off > 0; off >>= 1) {
            const unsigned long long o = __shfl_down(v, off, 64);
            v = o < v ? o : v;
        }
        const unsigned long long g = __shfl(v, 0, 64);
        if (lane == 0) {
            out_d[(size_t)qi * KSEL + it] = __uint_as_float((unsigned)(g >> 32));
            out_i[(size_t)qi * KSEL + it] = (float)(unsigned)(g & 0xFFFFFFFFu);
        }
        if (pmin == g) {
#pragma unroll
            for (int s = 0; s < 16; ++s) if (k[s] == g) k[s] = ~0ull;
            pmin = ~0ull;
#pragma unroll
            for (int s = 0; s < 16; ++s) pmin = k[s] < pmin ? k[s] : pmin;
        }
    }
}

extern "C" void kernel_launch(void* const* d_in, const int* in_sizes, int n_in,
                              void* d_out, int out_size, void* d_ws, size_t ws_size,
                              hipStream_t stream) {
    const float* x = (const float*)d_in[0];    // anchor_x [8192, 64] fp32
    float* sq = (float*)d_ws;                                        // 32 KB
    unsigned long long* tau0 =
        (unsigned long long*)((char*)d_ws + 32768);                  // 64 KB
    unsigned int* cnt = (unsigned int*)((char*)d_ws + 98304);        // 32 KB
    unsigned long long* lists =
        (unsigned long long*)((char*)d_ws + 131072);                 // 66.8 MB
    float* out_d = (float*)d_out;              // [8160, 32] distances
    float* out_i = out_d + (size_t)NQ * KSEL;  // [8160, 32] indices (as fp32)

    norms_kernel<<<NROWS / 256, 256, 0, stream>>>(x, sq);
    dim3 gp(64, P1LEN / TLC);                  // prefix: 64 qtiles x 4 ctiles
    prefix_kernel<<<gp, 256, 0, stream>>>(x, sq, lists);
    tausel_kernel<<<NQ, 64, 0, stream>>>(lists, tau0, cnt);
    dim3 g2(64, (NROWS - P1LEN) / TLC);        // tail: 64 x 60
    pass2_kernel<<<g2, 256, 0, stream>>>(x, sq, tau0, cnt, lists);
    merge_kernel<<<NQ, 64, 0, stream>>>(lists, cnt, out_d, out_i);
}